// Round 2
// baseline (624.901 us; speedup 1.0000x reference)
//
#include <hip/hip_runtime.h>
#include <stdint.h>

// ---------------------------------------------------------------------------
// cha_third_conv: polynomial channel expansion (L=8, orders 1..3) + 1x1 conv.
// GEMM view: M=B*H*W=12544, N=256, K=32 groups * 164 feats (padded to 192).
// This round: correctness-first direct transcription — features computed in
// ORIGINAL reference order from runtime pm2/pcm tables (no canonicalization),
// weights only cast bf16 + padded + MFMA-B-swizzled. MFMA core unchanged.
// ---------------------------------------------------------------------------

typedef short bf16x8 __attribute__((ext_vector_type(8)));
typedef float f32x4  __attribute__((ext_vector_type(4)));

__device__ __forceinline__ unsigned f2bf(float f) {
  unsigned u = __float_as_uint(f);
  return ((u + 0x7FFFu + ((u >> 16) & 1u)) >> 16) & 0xFFFFu;   // RTNE
}

// ---------------------------------------------------------------------------
// Prep: weight (256 x 5248 fp32, ORIGINAL feature order) -> bf16 in ws,
// padded 164->192 per group (pad = 0), B-swizzled layout:
//   ws[((sg*4 + q)*256 + n)*8 + j]  holds  w[n][g*164 + kk],
//   sg = g*6 + s,  kk = s*32 + q*8 + j  (kk >= 164 -> 0).
// Total 192*4*256*8 = 1,572,864 bf16 = 3.1 MB.
// ---------------------------------------------------------------------------
__global__ void prep_w(const float* __restrict__ w, short* __restrict__ wout) {
  int e = blockIdx.x * 256 + threadIdx.x;   // < 1,572,864
  int j  = e & 7;
  int n  = (e >> 3) & 255;
  int t2 = e >> 11;
  int q  = t2 & 3;
  int sg = t2 >> 2;                         // 0..191
  int g  = sg / 6;
  int s  = sg - g * 6;
  int kk = s * 32 + q * 8 + j;              // 0..191 (original order + pad)
  float val = (kk < 164) ? w[n * 5248 + g * 164 + kk] : 0.0f;
  wout[e] = (short)f2bf(val);
}

// ---------------------------------------------------------------------------
// Main fused kernel. Grid: (98 M-tiles of 128 pixels) x (4 N-tiles of 64).
// Block: 256 threads = 4 waves in 2(M) x 2(N); wave tile M64 x N32.
// LDS A-tile: 128 rows x 200 bf16; features 0..163 in ORIGINAL order,
// shorts 164..199 zeroed once.
// ---------------------------------------------------------------------------
#define ROW_S 200   // A-tile row stride in shorts (400 B)

__global__ __launch_bounds__(256, 2) void poly_gemm(
    const float* __restrict__ in, const short* __restrict__ wbf,
    const float* __restrict__ bias, const int* __restrict__ pm2,
    const int* __restrict__ pcm, float* __restrict__ out) {
  __shared__ __align__(16) short ldsA[128 * ROW_S];   // 51200 B
  __shared__ float ldsX[128 * 9];                     // 4608 B (stride 9: banks)
  __shared__ int tPa[36], tPb[36], tTc[120], tTp[120];

  const int tid  = threadIdx.x;
  const int m0   = blockIdx.x * 128;
  const int n0   = blockIdx.y * 64;
  const int lane = tid & 63;
  const int wave = tid >> 6;
  const int wm   = wave >> 1;       // M half
  const int wn   = wave & 1;        // N half
  const int quad = lane >> 4;
  const int l16  = lane & 15;

  // one-time init: runtime monomial tables + A-tile k-pad (shorts 164..199)
  if (tid < 36)  { tPa[tid] = pm2[2 * tid]; tPb[tid] = pm2[2 * tid + 1]; }
  if (tid < 120) { tTc[tid] = pcm[2 * tid]; tTp[tid] = pcm[2 * tid + 1]; }
  for (int i = tid; i < 128 * 36; i += 256) {
    int rr = i / 36, ss = 164 + (i - rr * 36);
    ldsA[rr * ROW_S + ss] = 0;
  }

  f32x4 acc[4][2];
#pragma unroll
  for (int mf = 0; mf < 4; mf++)
#pragma unroll
    for (int nf = 0; nf < 2; nf++) acc[mf][nf] = (f32x4){0.f, 0.f, 0.f, 0.f};

  const int pix  = tid & 127;
  const int part = tid >> 7;
  const int mg   = m0 + pix;
  const unsigned bb = (unsigned)mg / 3136u;
  const unsigned pp = (unsigned)mg - bb * 3136u;
  const float* xbase = in + (size_t)bb * 802816u + pp;

  for (int g = 0; g < 32; ++g) {
    __syncthreads();   // previous iteration's MFMA reads done (or init done)

    // stage A: per-pixel x[8] (this group's channels) into LDS
    if (part == 0) {
#pragma unroll
      for (int c = 0; c < 8; ++c) ldsX[pix * 9 + c] = xbase[(g * 8 + c) * 3136];
    }
    __syncthreads();

    // stage B: 164 features in ORIGINAL order, split across 2 parts
    {
      short* arow = &ldsA[pix * ROW_S];
      const float* xrow = &ldsX[pix * 9];
      for (int r = part * 82; r < part * 82 + 82; ++r) {
        float f;
        if (r < 8) {
          f = xrow[r];                                   // linear
        } else if (r < 44) {
          int rr = r - 8;                                // pm2 pair
          f = xrow[tPa[rr]] * xrow[tPb[rr]];
        } else {
          int rr = r - 44;                               // pcm triple: x * x2
          int pos = tTp[rr];
          float p = xrow[tPa[pos]] * xrow[tPb[pos]];     // x2 (same fp32 round)
          f = xrow[tTc[rr]] * p;
        }
        arow[r] = (short)f2bf(f);
      }
    }
    __syncthreads();   // A-tile ready

#pragma unroll
    for (int ks = 0; ks < 6; ++ks) {
      bf16x8 af[4];
#pragma unroll
      for (int mf = 0; mf < 4; mf++) {
        int row = wm * 64 + mf * 16 + l16;
        af[mf] = *(const bf16x8*)(ldsA + row * ROW_S + ks * 32 + quad * 8);
      }
      bf16x8 bfr[2];
      const int sg = g * 6 + ks;
#pragma unroll
      for (int nf = 0; nf < 2; nf++) {
        int n = n0 + wn * 32 + nf * 16 + l16;
        bfr[nf] = *(const bf16x8*)(wbf + (((size_t)(sg * 4 + quad) * 256 + n) << 3));
      }
#pragma unroll
      for (int mf = 0; mf < 4; mf++)
#pragma unroll
        for (int nf = 0; nf < 2; nf++)
          acc[mf][nf] = __builtin_amdgcn_mfma_f32_16x16x32_bf16(af[mf], bfr[nf], acc[mf][nf], 0, 0, 0);
    }
  }

  // epilogue: D col = lane&15 (out channel), row = quad*4 + r (pixel)
#pragma unroll
  for (int nf = 0; nf < 2; nf++) {
    const int col = n0 + wn * 32 + nf * 16 + l16;
    const float bv = bias[col];
#pragma unroll
    for (int mf = 0; mf < 4; mf++) {
#pragma unroll
      for (int r = 0; r < 4; r++) {
        int mg2 = m0 + wm * 64 + mf * 16 + quad * 4 + r;
        unsigned b2 = (unsigned)mg2 / 3136u;
        unsigned p2 = (unsigned)mg2 - b2 * 3136u;
        out[(size_t)b2 * 802816u + (size_t)col * 3136u + p2] = acc[mf][nf][r] + bv;
      }
    }
  }
}

extern "C" void kernel_launch(void* const* d_in, const int* in_sizes, int n_in,
                              void* d_out, int out_size, void* d_ws, size_t ws_size,
                              hipStream_t stream) {
  (void)in_sizes; (void)n_in; (void)out_size; (void)ws_size;
  const float* inp  = (const float*)d_in[0];
  const float* w    = (const float*)d_in[1];
  const float* bias = (const float*)d_in[2];
  const int*   pm2  = (const int*)d_in[3];
  const int*   pcm  = (const int*)d_in[4];
  short* wbf = (short*)d_ws;            // 3,145,728 B used

  prep_w<<<6144, 256, 0, stream>>>(w, wbf);
  poly_gemm<<<dim3(98, 4), 256, 0, stream>>>(inp, wbf, bias, pm2, pcm, (float*)d_out);
}